// Round 1
// baseline (544.084 us; speedup 1.0000x reference)
//
#include <hip/hip_runtime.h>

// Problem constants (match reference)
#define NNODES 64
#define NODE 4
#define EDGEF 2
#define HID 32
#define NFACT 3
#define NE 1024
#define NROWS (NE + NFACT)   // 1027
#define TPB 256

// Fused per-graph kernel: EdgeConv MLP + scatter-add + feature gather + head MLP + row-sum.
// One block per graph. All intermediates live in LDS/registers; no workspace traffic.
__global__ __launch_bounds__(TPB) void critic_fused(
    const float* __restrict__ x,          // [B*64, 4]
    const float* __restrict__ edge_attr,  // [B*1024, 2]
    const float* __restrict__ action,     // [B, 1027]
    const int*   __restrict__ es,         // [1024] per-graph src
    const int*   __restrict__ ed,         // [1024] per-graph dst
    const float* __restrict__ W1,         // [10, 32]
    const float* __restrict__ b1,         // [32]
    const float* __restrict__ W2,         // [32, 32]
    const float* __restrict__ b2,         // [32]
    const float* __restrict__ Wl,         // [73, 32]
    const float* __restrict__ bl,         // [32]
    const float* __restrict__ Wv,         // [32]
    const float* __restrict__ bv,         // [1]
    float* __restrict__ out)              // [B]
{
    const int b = blockIdx.x;
    const int tid = threadIdx.x;

    __shared__ float xs[NNODES][NODE];          // node input feats
    __shared__ float xpp[NNODES][HID + 1];      // conv output accumulator, +1 pad: atomic bank spread
    __shared__ float W1s[2 * NODE + EDGEF][HID];
    __shared__ float W2s[HID][HID];
    __shared__ float Wls[2 * (NODE + HID) + 1][HID];
    __shared__ float b1s[HID], b2s[HID], bls[HID], Wvs[HID];
    __shared__ float wred[TPB / 64];

    // ---- Stage A: stage weights + x, zero xpp ----
    for (int i = tid; i < 10 * HID; i += TPB)      ((float*)W1s)[i] = W1[i];
    for (int i = tid; i < HID * HID; i += TPB)     ((float*)W2s)[i] = W2[i];
    for (int i = tid; i < 73 * HID; i += TPB)      ((float*)Wls)[i] = Wl[i];
    if (tid < HID) {
        b1s[tid] = b1[tid];
        b2s[tid] = b2[tid];
        bls[tid] = bl[tid];
        Wvs[tid] = Wv[tid];
    }
    ((float*)xs)[tid] = x[b * (NNODES * NODE) + tid];   // exactly 256 floats
    for (int i = tid; i < NNODES * (HID + 1); i += TPB) ((float*)xpp)[i] = 0.0f;
    __syncthreads();

    // ---- Stage B: edge messages + LDS scatter-add at src ----
    for (int e = tid; e < NE; e += TPB) {
        const int s = es[e];
        const int d = ed[e];
        float f[10];
#pragma unroll
        for (int i = 0; i < NODE; i++) f[i] = xs[s][i];
#pragma unroll
        for (int i = 0; i < NODE; i++) f[NODE + i] = xs[d][i];
        const float2 ea = ((const float2*)edge_attr)[b * NE + e];
        f[8] = ea.x;
        f[9] = ea.y;

        float h1[HID];
#pragma unroll
        for (int k = 0; k < HID; k++) h1[k] = b1s[k];
#pragma unroll
        for (int i = 0; i < 10; i++) {
            const float fi = f[i];
#pragma unroll
            for (int k = 0; k < HID; k++) h1[k] += fi * W1s[i][k];
        }
#pragma unroll
        for (int k = 0; k < HID; k++) h1[k] = fmaxf(h1[k], 0.0f);

        float msg[HID];
#pragma unroll
        for (int k = 0; k < HID; k++) msg[k] = b2s[k];
#pragma unroll 4
        for (int j = 0; j < HID; j++) {
            const float hj = h1[j];
#pragma unroll
            for (int k = 0; k < HID; k++) msg[k] += hj * W2s[j][k];
        }
#pragma unroll
        for (int k = 0; k < HID; k++) atomicAdd(&xpp[s][k], msg[k]);
    }
    __syncthreads();

    // ---- Stage C: head MLP over 1027 rows, 2 rows/thread per pass ----
    float vsum = 0.0f;
    const float bvv = bv[0];

#pragma unroll
    for (int r0 = 0; r0 < NE; r0 += 2 * TPB) {
        const int rA = r0 + tid;
        const int rB = r0 + TPB + tid;
        const int naA = es[rA], nbA = ed[rA];
        const int naB = es[rB], nbB = ed[rB];

        float hidA[HID], hidB[HID];
#pragma unroll
        for (int k = 0; k < HID; k++) { hidA[k] = bls[k]; hidB[k] = bls[k]; }

#pragma unroll
        for (int i = 0; i < NODE; i++) {
            const float fA = xs[naA][i], fB = xs[naB][i];
#pragma unroll
            for (int k = 0; k < HID; k++) {
                const float w = Wls[i][k];
                hidA[k] += fA * w; hidB[k] += fB * w;
            }
        }
#pragma unroll 2
        for (int i = 0; i < HID; i++) {
            const float fA = xpp[naA][i], fB = xpp[naB][i];
#pragma unroll
            for (int k = 0; k < HID; k++) {
                const float w = Wls[NODE + i][k];
                hidA[k] += fA * w; hidB[k] += fB * w;
            }
        }
#pragma unroll
        for (int i = 0; i < NODE; i++) {
            const float fA = xs[nbA][i], fB = xs[nbB][i];
#pragma unroll
            for (int k = 0; k < HID; k++) {
                const float w = Wls[NODE + HID + i][k];
                hidA[k] += fA * w; hidB[k] += fB * w;
            }
        }
#pragma unroll 2
        for (int i = 0; i < HID; i++) {
            const float fA = xpp[nbA][i], fB = xpp[nbB][i];
#pragma unroll
            for (int k = 0; k < HID; k++) {
                const float w = Wls[2 * NODE + HID + i][k];
                hidA[k] += fA * w; hidB[k] += fB * w;
            }
        }
        {
            const float aA = action[b * NROWS + rA];
            const float aB = action[b * NROWS + rB];
#pragma unroll
            for (int k = 0; k < HID; k++) {
                const float w = Wls[72][k];
                hidA[k] += aA * w; hidB[k] += aB * w;
            }
        }
        float vA = bvv, vB = bvv;
#pragma unroll
        for (int k = 0; k < HID; k++) {
            vA += fmaxf(hidA[k], 0.0f) * Wvs[k];
            vB += fmaxf(hidB[k], 0.0f) * Wvs[k];
        }
        vsum += vA + vB;
    }

    // factory rows 1024..1026: node 61+i duplicated
    if (tid < NFACT) {
        const int r = NE + tid;
        const int na = NNODES - NFACT + tid;
        float hid[HID];
#pragma unroll
        for (int k = 0; k < HID; k++) hid[k] = bls[k];
#pragma unroll
        for (int i = 0; i < NODE; i++) {
            const float f = xs[na][i];
#pragma unroll
            for (int k = 0; k < HID; k++)
                hid[k] += f * (Wls[i][k] + Wls[NODE + HID + i][k]);
        }
#pragma unroll 2
        for (int i = 0; i < HID; i++) {
            const float f = xpp[na][i];
#pragma unroll
            for (int k = 0; k < HID; k++)
                hid[k] += f * (Wls[NODE + i][k] + Wls[2 * NODE + HID + i][k]);
        }
        const float a = action[b * NROWS + r];
        float v = bvv;
#pragma unroll
        for (int k = 0; k < HID; k++) {
            const float h = fmaxf(hid[k] + a * Wls[72][k], 0.0f);
            v += h * Wvs[k];
        }
        vsum += v;
    }

    // ---- block reduction ----
#pragma unroll
    for (int off = 32; off > 0; off >>= 1)
        vsum += __shfl_down(vsum, off, 64);
    if ((tid & 63) == 0) wred[tid >> 6] = vsum;
    __syncthreads();
    if (tid == 0) {
        float t = 0.0f;
#pragma unroll
        for (int w = 0; w < TPB / 64; w++) t += wred[w];
        out[b] = t;
    }
}

extern "C" void kernel_launch(void* const* d_in, const int* in_sizes, int n_in,
                              void* d_out, int out_size, void* d_ws, size_t ws_size,
                              hipStream_t stream) {
    const float* x         = (const float*)d_in[0];
    // d_in[1] = edge_index (unused: identical info via es/ed + per-graph offset)
    const float* edge_attr = (const float*)d_in[2];
    const float* action    = (const float*)d_in[3];
    const int*   es        = (const int*)d_in[4];
    const int*   ed        = (const int*)d_in[5];
    const float* W1        = (const float*)d_in[6];
    const float* b1        = (const float*)d_in[7];
    const float* W2        = (const float*)d_in[8];
    const float* b2        = (const float*)d_in[9];
    const float* Wl        = (const float*)d_in[10];
    const float* bl        = (const float*)d_in[11];
    const float* Wv        = (const float*)d_in[12];
    const float* bv        = (const float*)d_in[13];
    float* out = (float*)d_out;

    critic_fused<<<dim3(out_size), dim3(TPB), 0, stream>>>(
        x, edge_attr, action, es, ed, W1, b1, W2, b2, Wl, bl, Wv, bv, out);
}

// Round 2
// 316.999 us; speedup vs baseline: 1.7164x; 1.7164x over previous
//
#include <hip/hip_runtime.h>

// Problem constants
#define NNODES 64
#define NODE 4
#define HID 32
#define NFACT 3
#define NE 1024
#define NROWS (NE + NFACT)   // 1027
#define TPB 256
#define XSTR 33              // xpp row stride (floats): odd -> scatter-atomic banks spread
#define QSTR 36              // Q/P row stride (floats): 144 B, 16B-aligned float4 rows, bank offset 4/row

// Fused per-graph kernel, factored form:
//   Q1[n] = b1 + x[n] @ W1[0:4]        Q2[n] = x[n] @ W1[4:8]
//   h1(e) = relu(Q1[s] + Q2[d] + ea.x*W1[8] + ea.y*W1[9]);  msg = h1 @ W2 + b2
//   xpp[s] += msg (LDS atomics)
//   P1[n] = bl + [x,xpp][n] @ Wl[0:36]  P2[n] = [x,xpp][n] @ Wl[36:72]
//   v(r)  = bv + relu(P1[na] + P2[nb] + a*Wl[72]) . Wv ;  out[b] = sum_r v(r)
// All weight reads use wave-uniform global indices -> s_load (SMEM), keeping the
// CU-shared LDS port free for the per-lane Q/P/xpp gathers (float4, bank-spread).
__global__ __launch_bounds__(TPB, 4) void critic_fused(
    const float* __restrict__ x,          // [B*64, 4]
    const float* __restrict__ edge_attr,  // [B*1024, 2]
    const float* __restrict__ action,     // [B, 1027]
    const int*   __restrict__ es,         // [1024]
    const int*   __restrict__ ed,         // [1024]
    const float* __restrict__ W1,         // [10, 32]
    const float* __restrict__ b1,         // [32]
    const float* __restrict__ W2,         // [32, 32]
    const float* __restrict__ b2,         // [32]
    const float* __restrict__ Wl,         // [73, 32]
    const float* __restrict__ bl,         // [32]
    const float* __restrict__ Wv,         // [32]
    const float* __restrict__ bv,         // [1]
    float* __restrict__ out)              // [B]
{
    const int b = blockIdx.x;
    const int tid = threadIdx.x;

    __shared__ float4 xs4[NNODES];             // node input feats (float4/node)
    __shared__ float  xpp[NNODES * XSTR];      // conv accumulator (atomic target)
    __shared__ float  qp[2][NNODES * QSTR];    // Q1/Q2 during edge stage; P1/P2 after
    __shared__ float  wred[TPB / 64];

    // ---- Stage A: stage x, zero xpp ----
    if (tid < NNODES) xs4[tid] = ((const float4*)x)[b * NNODES + tid];
    for (int i = tid; i < NNODES * XSTR; i += TPB) xpp[i] = 0.0f;
    __syncthreads();

    const int n  = tid & 63;       // node owned in Q/P stages (wave-uniform kq)
    const int kq = tid >> 6;       // k-block 0..3 (8 outputs each)

    // ---- Stage Q: per-node first-layer partials ----
    {
        const float4 xv = xs4[n];
        const float xa[4] = {xv.x, xv.y, xv.z, xv.w};
        float q1[8], q2[8];
#pragma unroll
        for (int kk = 0; kk < 8; kk++) {
            const int k = kq * 8 + kk;
            float a1 = b1[k];
            float a2 = 0.0f;
#pragma unroll
            for (int i = 0; i < 4; i++) {
                a1 += xa[i] * W1[i * HID + k];          // s_load (uniform)
                a2 += xa[i] * W1[(4 + i) * HID + k];    // s_load (uniform)
            }
            q1[kk] = a1;
            q2[kk] = a2;
        }
        float4* q1w = (float4*)&qp[0][n * QSTR + kq * 8];
        float4* q2w = (float4*)&qp[1][n * QSTR + kq * 8];
        q1w[0] = make_float4(q1[0], q1[1], q1[2], q1[3]);
        q1w[1] = make_float4(q1[4], q1[5], q1[6], q1[7]);
        q2w[0] = make_float4(q2[0], q2[1], q2[2], q2[3]);
        q2w[1] = make_float4(q2[4], q2[5], q2[6], q2[7]);
    }
    __syncthreads();

    // ---- Stage B: edge messages + scatter-add ----
    {
        const float2* ea2 = (const float2*)edge_attr + (size_t)b * NE;
        for (int e = tid; e < NE; e += TPB) {
            const int s = es[e];
            const int d = ed[e];
            const float2 ea = ea2[e];
            const float4* q1v = (const float4*)&qp[0][s * QSTR];
            const float4* q2v = (const float4*)&qp[1][d * QSTR];

            float h1[HID];
#pragma unroll
            for (int q = 0; q < 8; q++) {
                const float4 qa = q1v[q];
                const float4 qb = q2v[q];
                const int k = q * 4;
                h1[k + 0] = fmaxf(qa.x + qb.x + ea.x * W1[8 * HID + k + 0] + ea.y * W1[9 * HID + k + 0], 0.0f);
                h1[k + 1] = fmaxf(qa.y + qb.y + ea.x * W1[8 * HID + k + 1] + ea.y * W1[9 * HID + k + 1], 0.0f);
                h1[k + 2] = fmaxf(qa.z + qb.z + ea.x * W1[8 * HID + k + 2] + ea.y * W1[9 * HID + k + 2], 0.0f);
                h1[k + 3] = fmaxf(qa.w + qb.w + ea.x * W1[8 * HID + k + 3] + ea.y * W1[9 * HID + k + 3], 0.0f);
            }

            float msg[HID];
#pragma unroll
            for (int k = 0; k < HID; k++) msg[k] = b2[k];   // s_load (uniform)
#pragma unroll
            for (int j = 0; j < HID; j++) {
                const float hj = h1[j];
#pragma unroll
                for (int k = 0; k < HID; k++)
                    msg[k] += hj * W2[j * HID + k];          // s_load (uniform)
            }

            float* xr = &xpp[s * XSTR];
#pragma unroll
            for (int k = 0; k < HID; k++) atomicAdd(&xr[k], msg[k]);
        }
    }
    __syncthreads();

    // ---- Stage P: per-node head-layer projections (reuse qp storage) ----
    {
        const float4 xv = xs4[n];
        const float xa[4] = {xv.x, xv.y, xv.z, xv.w};
        float xp[HID];
        const float* xr = &xpp[n * XSTR];
#pragma unroll
        for (int j = 0; j < HID; j++) xp[j] = xr[j];  // b32, stride-33 -> conflict-free

        float p1[8], p2[8];
#pragma unroll
        for (int kk = 0; kk < 8; kk++) {
            const int k = kq * 8 + kk;
            p1[kk] = bl[k];
            p2[kk] = 0.0f;
#pragma unroll
            for (int i = 0; i < 4; i++) {
                p1[kk] += xa[i] * Wl[i * HID + k];
                p2[kk] += xa[i] * Wl[(36 + i) * HID + k];
            }
        }
#pragma unroll
        for (int j = 0; j < HID; j++) {
            const float xj = xp[j];
#pragma unroll
            for (int kk = 0; kk < 8; kk++) {
                const int k = kq * 8 + kk;
                p1[kk] += xj * Wl[(4 + j) * HID + k];
                p2[kk] += xj * Wl[(40 + j) * HID + k];
            }
        }
        float4* p1w = (float4*)&qp[0][n * QSTR + kq * 8];
        float4* p2w = (float4*)&qp[1][n * QSTR + kq * 8];
        p1w[0] = make_float4(p1[0], p1[1], p1[2], p1[3]);
        p1w[1] = make_float4(p1[4], p1[5], p1[6], p1[7]);
        p2w[0] = make_float4(p2[0], p2[1], p2[2], p2[3]);
        p2w[1] = make_float4(p2[4], p2[5], p2[6], p2[7]);
    }
    __syncthreads();

    // ---- Stage C: per-row combine + value head ----
    float vsum = 0.0f;
    {
        const float* actb = action + (size_t)b * NROWS;
        const float bvv = bv[0];
        for (int r = tid; r < NROWS; r += TPB) {
            int na, nb;
            if (r < NE) { na = es[r]; nb = ed[r]; }
            else        { na = NNODES - NFACT + (r - NE); nb = na; }
            const float a = actb[r];
            const float4* p1v = (const float4*)&qp[0][na * QSTR];
            const float4* p2v = (const float4*)&qp[1][nb * QSTR];
            float v = bvv;
#pragma unroll
            for (int q = 0; q < 8; q++) {
                const float4 pa = p1v[q];
                const float4 pb = p2v[q];
                const int k = q * 4;
                v += fmaxf(pa.x + pb.x + a * Wl[72 * HID + k + 0], 0.0f) * Wv[k + 0];
                v += fmaxf(pa.y + pb.y + a * Wl[72 * HID + k + 1], 0.0f) * Wv[k + 1];
                v += fmaxf(pa.z + pb.z + a * Wl[72 * HID + k + 2], 0.0f) * Wv[k + 2];
                v += fmaxf(pa.w + pb.w + a * Wl[72 * HID + k + 3], 0.0f) * Wv[k + 3];
            }
            vsum += v;
        }
    }

    // ---- block reduction ----
#pragma unroll
    for (int off = 32; off > 0; off >>= 1)
        vsum += __shfl_down(vsum, off, 64);
    if ((tid & 63) == 0) wred[tid >> 6] = vsum;
    __syncthreads();
    if (tid == 0) {
        float t = 0.0f;
#pragma unroll
        for (int w = 0; w < TPB / 64; w++) t += wred[w];
        out[b] = t;
    }
}

extern "C" void kernel_launch(void* const* d_in, const int* in_sizes, int n_in,
                              void* d_out, int out_size, void* d_ws, size_t ws_size,
                              hipStream_t stream) {
    const float* x         = (const float*)d_in[0];
    // d_in[1] = edge_index (redundant: es/ed + per-graph offset)
    const float* edge_attr = (const float*)d_in[2];
    const float* action    = (const float*)d_in[3];
    const int*   es        = (const int*)d_in[4];
    const int*   ed        = (const int*)d_in[5];
    const float* W1        = (const float*)d_in[6];
    const float* b1        = (const float*)d_in[7];
    const float* W2        = (const float*)d_in[8];
    const float* b2        = (const float*)d_in[9];
    const float* Wl        = (const float*)d_in[10];
    const float* bl        = (const float*)d_in[11];
    const float* Wv        = (const float*)d_in[12];
    const float* bv        = (const float*)d_in[13];
    float* out = (float*)d_out;

    critic_fused<<<dim3(out_size), dim3(TPB), 0, stream>>>(
        x, edge_attr, action, es, ed, W1, b1, W2, b2, Wl, bl, Wv, bv, out);
}

// Round 3
// 274.354 us; speedup vs baseline: 1.9831x; 1.1554x over previous
//
#include <hip/hip_runtime.h>

// Problem constants
#define NNODES 64
#define HID 32
#define NFACT 3
#define NE 1024
#define NROWS (NE + NFACT)   // 1027
#define TPB 256
#define XSTR 33              // xpp row stride (floats): odd -> atomic banks spread
#define QSTR 36              // Q/P row stride (floats): float4-aligned rows

typedef short bf16x8 __attribute__((ext_vector_type(8)));   // 8 bf16 (4 VGPRs)
typedef float f32x4  __attribute__((ext_vector_type(4)));   // MFMA accumulator

// fp32 -> bf16 with round-to-nearest-even
__device__ __forceinline__ short f2bf(float f) {
    unsigned u = __builtin_bit_cast(unsigned, f);
    u += 0x7fffu + ((u >> 16) & 1u);
    return (short)(u >> 16);
}

// Fused per-graph kernel, factored form + MFMA edge-GEMM:
//   Q1[n] = b1 + x[n] @ W1[0:4]        Q2[n] = x[n] @ W1[4:8]
//   h1(e) = relu(Q1[s] + Q2[d] + ea.x*W1[8] + ea.y*W1[9])
//   msg   = h1 @ W2 (+ b2)   -- 16x16x32 bf16 MFMA, W2 held as B-frags in VGPRs
//   xpp[s] += msg            -- LDS ds_add scatter in MFMA C-layout
//   P1[n] = bl + [x,xpp][n] @ Wl[0:36]  P2[n] = [x,xpp][n] @ Wl[36:72]
//   v(r)  = bv + relu(P1[na] + P2[nb] + a*Wl[72]) . Wv ;  out[b] = sum_r v(r)
__global__ __launch_bounds__(TPB, 4) void critic_fused(
    const float* __restrict__ x,          // [B*64, 4]
    const float* __restrict__ edge_attr,  // [B*1024, 2]
    const float* __restrict__ action,     // [B, 1027]
    const int*   __restrict__ es,         // [1024]
    const int*   __restrict__ ed,         // [1024]
    const float* __restrict__ W1,         // [10, 32]
    const float* __restrict__ b1,         // [32]
    const float* __restrict__ W2,         // [32, 32]
    const float* __restrict__ b2,         // [32]
    const float* __restrict__ Wl,         // [73, 32]
    const float* __restrict__ bl,         // [32]
    const float* __restrict__ Wv,         // [32]
    const float* __restrict__ bv,         // [1]
    float* __restrict__ out)              // [B]
{
    const int b   = blockIdx.x;
    const int tid = threadIdx.x;
    const int lane = tid & 63;
    const int wv   = tid >> 6;

    __shared__ float4 xs4[NNODES];             // node input feats
    __shared__ float  xpp[NNODES * XSTR];      // conv accumulator (atomic target)
    __shared__ float  qp[2][NNODES * QSTR];    // Q1/Q2 during edge stage; P1/P2 after
    __shared__ float  wred[TPB / 64];

    // ---- Stage A: stage x, zero xpp ----
    if (tid < NNODES) xs4[tid] = ((const float4*)x)[b * NNODES + tid];
    for (int i = tid; i < NNODES * XSTR; i += TPB) xpp[i] = 0.0f;
    __syncthreads();

    const int n  = tid & 63;       // node owned in Q/P stages
    const int kq = tid >> 6;       // k-block 0..3 (wave-uniform)

    // ---- Stage Q: per-node first-layer partials ----
    {
        const float4 xv = xs4[n];
        const float xa[4] = {xv.x, xv.y, xv.z, xv.w};
        float q1[8], q2[8];
#pragma unroll
        for (int kk = 0; kk < 8; kk++) {
            const int k = kq * 8 + kk;
            float a1 = b1[k];
            float a2 = 0.0f;
#pragma unroll
            for (int i = 0; i < 4; i++) {
                a1 += xa[i] * W1[i * HID + k];          // s_load (uniform)
                a2 += xa[i] * W1[(4 + i) * HID + k];
            }
            q1[kk] = a1;
            q2[kk] = a2;
        }
        float4* q1w = (float4*)&qp[0][n * QSTR + kq * 8];
        float4* q2w = (float4*)&qp[1][n * QSTR + kq * 8];
        q1w[0] = make_float4(q1[0], q1[1], q1[2], q1[3]);
        q1w[1] = make_float4(q1[4], q1[5], q1[6], q1[7]);
        q2w[0] = make_float4(q2[0], q2[1], q2[2], q2[3]);
        q2w[1] = make_float4(q2[4], q2[5], q2[6], q2[7]);
    }
    __syncthreads();

    // ---- Stage B: edge messages via MFMA + LDS scatter-add ----
    {
        const float2* ea2 = (const float2*)edge_attr + (size_t)b * NE;
        const int quad = lane >> 4;
        const int m16  = lane & 15;
        const int kh   = quad * 8;     // this lane's K-slice in A/B fragments

        // lane-constant edge-attr weights (tile-invariant, hoisted)
        const float4* w8p = (const float4*)&W1[8 * HID + kh];
        const float4* w9p = (const float4*)&W1[9 * HID + kh];
        const float4 w8a = w8p[0], w8b = w8p[1];
        const float4 w9a = w9p[0], w9b = w9p[1];
        const float b2c0 = b2[m16];
        const float b2c1 = b2[16 + m16];

        // B-fragments of W2 column halves: B[k=kh+j][col]
        bf16x8 bf0, bf1;
#pragma unroll
        for (int j = 0; j < 8; j++) {
            bf0[j] = f2bf(W2[(kh + j) * HID + m16]);
            bf1[j] = f2bf(W2[(kh + j) * HID + 16 + m16]);
        }

        for (int t = wv; t < NE / 16; t += TPB / 64) {
            // A-fragment: rows = edges t*16+m16, k = kh..kh+8
            const int ea_e = t * 16 + m16;
            const int s_a = es[ea_e];                 // global, 64B broadcast
            const int d_a = ed[ea_e];
            const float2 ea = ea2[ea_e];
            const float4* q1p = (const float4*)&qp[0][s_a * QSTR + kh];
            const float4* q2p = (const float4*)&qp[1][d_a * QSTR + kh];
            const float4 qa0 = q1p[0], qa1 = q1p[1];
            const float4 qb0 = q2p[0], qb1 = q2p[1];

            bf16x8 af;
            af[0] = f2bf(fmaxf(qa0.x + qb0.x + ea.x * w8a.x + ea.y * w9a.x, 0.f));
            af[1] = f2bf(fmaxf(qa0.y + qb0.y + ea.x * w8a.y + ea.y * w9a.y, 0.f));
            af[2] = f2bf(fmaxf(qa0.z + qb0.z + ea.x * w8a.z + ea.y * w9a.z, 0.f));
            af[3] = f2bf(fmaxf(qa0.w + qb0.w + ea.x * w8a.w + ea.y * w9a.w, 0.f));
            af[4] = f2bf(fmaxf(qa1.x + qb1.x + ea.x * w8b.x + ea.y * w9b.x, 0.f));
            af[5] = f2bf(fmaxf(qa1.y + qb1.y + ea.x * w8b.y + ea.y * w9b.y, 0.f));
            af[6] = f2bf(fmaxf(qa1.z + qb1.z + ea.x * w8b.z + ea.y * w9b.z, 0.f));
            af[7] = f2bf(fmaxf(qa1.w + qb1.w + ea.x * w8b.w + ea.y * w9b.w, 0.f));

            f32x4 c0 = {0.f, 0.f, 0.f, 0.f};
            f32x4 c1 = {0.f, 0.f, 0.f, 0.f};
            c0 = __builtin_amdgcn_mfma_f32_16x16x32_bf16(af, bf0, c0, 0, 0, 0);
            c1 = __builtin_amdgcn_mfma_f32_16x16x32_bf16(af, bf1, c1, 0, 0, 0);

            // C layout: row = quad*4+r (edge), col = m16 (k); scatter to xpp
            const int rowbase = t * 16 + quad * 4;
#pragma unroll
            for (int r = 0; r < 4; r++) {
                const int sn = es[rowbase + r];       // global, 64B broadcast
                float* xr = &xpp[sn * XSTR];
                atomicAdd(&xr[m16],      c0[r] + b2c0);
                atomicAdd(&xr[16 + m16], c1[r] + b2c1);
            }
        }
    }
    __syncthreads();

    // ---- Stage P: per-node head-layer projections (reuse qp storage) ----
    {
        const float4 xv = xs4[n];
        const float xa[4] = {xv.x, xv.y, xv.z, xv.w};
        float xp[HID];
        const float* xr = &xpp[n * XSTR];
#pragma unroll
        for (int j = 0; j < HID; j++) xp[j] = xr[j];  // stride-33 -> conflict-free

        float p1[8], p2[8];
#pragma unroll
        for (int kk = 0; kk < 8; kk++) {
            const int k = kq * 8 + kk;
            p1[kk] = bl[k];
            p2[kk] = 0.0f;
#pragma unroll
            for (int i = 0; i < 4; i++) {
                p1[kk] += xa[i] * Wl[i * HID + k];
                p2[kk] += xa[i] * Wl[(36 + i) * HID + k];
            }
        }
#pragma unroll
        for (int j = 0; j < HID; j++) {
            const float xj = xp[j];
#pragma unroll
            for (int kk = 0; kk < 8; kk++) {
                const int k = kq * 8 + kk;
                p1[kk] += xj * Wl[(4 + j) * HID + k];
                p2[kk] += xj * Wl[(40 + j) * HID + k];
            }
        }
        __syncthreads();   // xpp reads done before qp overwrite? qp != xpp, but P writes overwrite Q reads used by no one now; keep barrier ordering with stage B readers
        float4* p1w = (float4*)&qp[0][n * QSTR + kq * 8];
        float4* p2w = (float4*)&qp[1][n * QSTR + kq * 8];
        p1w[0] = make_float4(p1[0], p1[1], p1[2], p1[3]);
        p1w[1] = make_float4(p1[4], p1[5], p1[6], p1[7]);
        p2w[0] = make_float4(p2[0], p2[1], p2[2], p2[3]);
        p2w[1] = make_float4(p2[4], p2[5], p2[6], p2[7]);
    }
    __syncthreads();

    // ---- Stage C: per-row combine + value head ----
    float vsum = 0.0f;
    {
        const float* actb = action + (size_t)b * NROWS;
        const float bvv = bv[0];
        for (int r = tid; r < NROWS; r += TPB) {
            int na, nb;
            if (r < NE) { na = es[r]; nb = ed[r]; }
            else        { na = NNODES - NFACT + (r - NE); nb = na; }
            const float a = actb[r];
            const float4* p1v = (const float4*)&qp[0][na * QSTR];
            const float4* p2v = (const float4*)&qp[1][nb * QSTR];
            float v = bvv;
#pragma unroll
            for (int q = 0; q < 8; q++) {
                const float4 pa = p1v[q];
                const float4 pb = p2v[q];
                const int k = q * 4;
                v += fmaxf(pa.x + pb.x + a * Wl[72 * HID + k + 0], 0.0f) * Wv[k + 0];
                v += fmaxf(pa.y + pb.y + a * Wl[72 * HID + k + 1], 0.0f) * Wv[k + 1];
                v += fmaxf(pa.z + pb.z + a * Wl[72 * HID + k + 2], 0.0f) * Wv[k + 2];
                v += fmaxf(pa.w + pb.w + a * Wl[72 * HID + k + 3], 0.0f) * Wv[k + 3];
            }
            vsum += v;
        }
    }

    // ---- block reduction ----
#pragma unroll
    for (int off = 32; off > 0; off >>= 1)
        vsum += __shfl_down(vsum, off, 64);
    if ((tid & 63) == 0) wred[tid >> 6] = vsum;
    __syncthreads();
    if (tid == 0) {
        float t = 0.0f;
#pragma unroll
        for (int w = 0; w < TPB / 64; w++) t += wred[w];
        out[b] = t;
    }
}

extern "C" void kernel_launch(void* const* d_in, const int* in_sizes, int n_in,
                              void* d_out, int out_size, void* d_ws, size_t ws_size,
                              hipStream_t stream) {
    const float* x         = (const float*)d_in[0];
    // d_in[1] = edge_index (redundant: es/ed + per-graph offset)
    const float* edge_attr = (const float*)d_in[2];
    const float* action    = (const float*)d_in[3];
    const int*   es        = (const int*)d_in[4];
    const int*   ed        = (const int*)d_in[5];
    const float* W1        = (const float*)d_in[6];
    const float* b1        = (const float*)d_in[7];
    const float* W2        = (const float*)d_in[8];
    const float* b2        = (const float*)d_in[9];
    const float* Wl        = (const float*)d_in[10];
    const float* bl        = (const float*)d_in[11];
    const float* Wv        = (const float*)d_in[12];
    const float* bv        = (const float*)d_in[13];
    float* out = (float*)d_out;

    critic_fused<<<dim3(out_size), dim3(TPB), 0, stream>>>(
        x, edge_attr, action, es, ed, W1, b1, W2, b2, Wl, bl, Wv, bv, out);
}